// Round 1
// baseline (396.114 us; speedup 1.0000x reference)
//
#include <hip/hip_runtime.h>
#include <math.h>

#define N 8192
#define C 10
#define D 6
#define NUM_ITERS 5
#define JCHUNKS 16
#define JT (N / JCHUNKS)   /* 512 j's per chunk */
#define ITILES (N / 256)   /* 32 */
#define BLOCK 256
#define LOG2E 1.44269504088896340736f
#define CSP (LOG2E / 64.0f)   /* spatial dot scale: feat[:3]/8 -> dot/64, times log2e */

// Workspace layout (floats):
//   fj  : [N][8]   = {f0..f5, hs' = 0.5*||f[:3]||^2 * LOG2E/64, hb' = 0.5*||f||^2 * LOG2E}
//   pp  : [N][12]  = {p0..p9, 0, 0}  (padded to float4 multiple)
//   acc : [20][N]  atomic accumulator: rows 0..9 spatial_out, 10..19 bilateral_out
#define WS_FJ   0
#define WS_PP   (N * 8)
#define WS_ACC  (N * 8 + N * 12)

__global__ __launch_bounds__(BLOCK) void setup_kernel(const float* __restrict__ feat,
                                                      float* __restrict__ fj) {
    int n = blockIdx.x * BLOCK + threadIdx.x;
    float f[D];
#pragma unroll
    for (int d = 0; d < D; ++d) f[d] = feat[d * N + n];
    float r3 = f[0] * f[0] + f[1] * f[1] + f[2] * f[2];
    float r6 = r3 + f[3] * f[3] + f[4] * f[4] + f[5] * f[5];
#pragma unroll
    for (int d = 0; d < D; ++d) fj[n * 8 + d] = f[d];
    fj[n * 8 + 6] = 0.5f * r3 * CSP;
    fj[n * 8 + 7] = 0.5f * r6 * LOG2E;
}

// do_filter=0: q = unaries (acc is poison -> just zero it). is_last=1: write q to out.
__global__ __launch_bounds__(BLOCK) void combine_kernel(
    const float* __restrict__ unaries, const float* __restrict__ SW,
    const float* __restrict__ BW, const float* __restrict__ CM,
    float* __restrict__ acc, float* __restrict__ pp, float* __restrict__ out,
    int do_filter, int is_last) {
    __shared__ float sSW[100], sBW[100], sCM[100];
    int t = threadIdx.x;
    if (t < 100) { sSW[t] = SW[t]; sBW[t] = BW[t]; sCM[t] = CM[t]; }
    __syncthreads();
    int n = blockIdx.x * BLOCK + t;

    float q[C];
    if (do_filter) {
        float sp[C], bl[C];
#pragma unroll
        for (int k = 0; k < C; ++k) {
            sp[k] = acc[k * N + n];        acc[k * N + n] = 0.0f;
            bl[k] = acc[(C + k) * N + n];  acc[(C + k) * N + n] = 0.0f;
        }
        float msg[C];
#pragma unroll
        for (int c = 0; c < C; ++c) {
            float m = 0.0f;
#pragma unroll
            for (int k = 0; k < C; ++k)
                m += sSW[c * C + k] * sp[k] + sBW[c * C + k] * bl[k];
            msg[c] = m;
        }
#pragma unroll
        for (int c = 0; c < C; ++c) {
            float pw = 0.0f;
#pragma unroll
            for (int k = 0; k < C; ++k) pw += sCM[c * C + k] * msg[k];
            q[c] = unaries[c * N + n] - pw;
        }
    } else {
#pragma unroll
        for (int c = 0; c < C; ++c) q[c] = unaries[c * N + n];
#pragma unroll
        for (int k = 0; k < 2 * C; ++k) acc[k * N + n] = 0.0f;
    }

    if (is_last) {
#pragma unroll
        for (int c = 0; c < C; ++c) out[c * N + n] = q[c];
    } else {
        float m = q[0];
#pragma unroll
        for (int c = 1; c < C; ++c) m = fmaxf(m, q[c]);
        float e[C], s = 0.0f;
#pragma unroll
        for (int c = 0; c < C; ++c) {
            e[c] = __builtin_amdgcn_exp2f((q[c] - m) * LOG2E);
            s += e[c];
        }
        float inv = 1.0f / s;
#pragma unroll
        for (int c = 0; c < C; ++c) pp[n * 12 + c] = e[c] * inv;
        pp[n * 12 + 10] = 0.0f;
        pp[n * 12 + 11] = 0.0f;
    }
}

__global__ __launch_bounds__(BLOCK, 2) void filter_kernel(
    const float* __restrict__ fj, const float* __restrict__ pp,
    float* __restrict__ acc) {
    __shared__ float4 sF[JT * 2];   // [j][8 floats]  = 16 KB
    __shared__ float4 sP[JT * 3];   // [j][12 floats] = 24 KB
    int t = threadIdx.x;
    int itile = blockIdx.x;
    int jc = blockIdx.y;
    int jbase = jc * JT;

    // stage j-chunk into LDS (coalesced float4)
    const float4* gF = (const float4*)(fj + (size_t)jbase * 8);
    for (int k = t; k < JT * 2; k += BLOCK) sF[k] = gF[k];
    const float4* gP = (const float4*)(pp + (size_t)jbase * 12);
    for (int k = t; k < JT * 3; k += BLOCK) sP[k] = gP[k];
    __syncthreads();

    int i = itile * BLOCK + t;
    float4 fiA = ((const float4*)fj)[i * 2 + 0];  // f0..f3
    float4 fiB = ((const float4*)fj)[i * 2 + 1];  // f4, f5, hs'_i, hb'_i

    float asp[C], abl[C];
#pragma unroll
    for (int k = 0; k < C; ++k) { asp[k] = 0.0f; abl[k] = 0.0f; }

#pragma unroll 4
    for (int j = 0; j < JT; ++j) {
        float4 fA = sF[j * 2 + 0];
        float4 fB = sF[j * 2 + 1];
        float d3 = fiA.x * fA.x + fiA.y * fA.y + fiA.z * fA.z;
        float d6 = d3 + fiA.w * fA.w + fiB.x * fB.x + fiB.y * fB.y;
        // spatial: exp2(d3*CSP - hs'_i - hs'_j) ; bilateral: exp2(d6*LOG2E - hb'_i - hb'_j)
        float wsp = __builtin_amdgcn_exp2f(fmaf(d3, CSP, -fiB.z) - fB.z);
        float wbl = __builtin_amdgcn_exp2f(fmaf(d6, LOG2E, -fiB.w) - fB.w);
        float4 p0 = sP[j * 3 + 0];
        float4 p1 = sP[j * 3 + 1];
        float4 p2 = sP[j * 3 + 2];
        float pj[C] = {p0.x, p0.y, p0.z, p0.w, p1.x, p1.y, p1.z, p1.w, p2.x, p2.y};
#pragma unroll
        for (int k = 0; k < C; ++k) {
            asp[k] = fmaf(wsp, pj[k], asp[k]);
            abl[k] = fmaf(wbl, pj[k], abl[k]);
        }
    }

#pragma unroll
    for (int k = 0; k < C; ++k) {
        atomicAdd(&acc[k * N + i], asp[k]);
        atomicAdd(&acc[(C + k) * N + i], abl[k]);
    }
}

extern "C" void kernel_launch(void* const* d_in, const int* in_sizes, int n_in,
                              void* d_out, int out_size, void* d_ws, size_t ws_size,
                              hipStream_t stream) {
    const float* unaries = (const float*)d_in[0];   // [10, 8192]
    const float* feat    = (const float*)d_in[1];   // [6, 8192]
    const float* SW      = (const float*)d_in[2];   // [10,10]
    const float* BW      = (const float*)d_in[3];   // [10,10]
    const float* CM      = (const float*)d_in[4];   // [10,10]
    float* out = (float*)d_out;

    float* ws  = (float*)d_ws;
    float* fj  = ws + WS_FJ;
    float* pp  = ws + WS_PP;
    float* acc = ws + WS_ACC;

    setup_kernel<<<N / BLOCK, BLOCK, 0, stream>>>(feat, fj);
    // initial softmax of unaries -> pp ; zero acc
    combine_kernel<<<N / BLOCK, BLOCK, 0, stream>>>(unaries, SW, BW, CM, acc, pp, out, 0, 0);
    for (int it = 1; it <= NUM_ITERS; ++it) {
        filter_kernel<<<dim3(ITILES, JCHUNKS), BLOCK, 0, stream>>>(fj, pp, acc);
        combine_kernel<<<N / BLOCK, BLOCK, 0, stream>>>(unaries, SW, BW, CM, acc, pp, out,
                                                        1, it == NUM_ITERS ? 1 : 0);
    }
}

// Round 2
// 390.339 us; speedup vs baseline: 1.0148x; 1.0148x over previous
//
#include <hip/hip_runtime.h>
#include <math.h>

#define N 8192
#define C 10
#define D 6
#define NUM_ITERS 5
#define JCHUNKS 32
#define JT (N / JCHUNKS)   /* 256 j's per chunk */
#define ITILES (N / 256)   /* 32 */
#define BLOCK 256
#define LOG2E 1.44269504088896340736f
#define CSP (LOG2E / 64.0f)   /* spatial dot scale: feat[:3]/8 -> dot/64, times log2e */

// Workspace layout (floats):
//   fj  : [N][8]   = {f0..f5, hs' = 0.5*||f[:3]||^2 * LOG2E/64, hb' = 0.5*||f||^2 * LOG2E}
//   pp  : [N][12]  = {p0..p9, 0, 0}  (padded to float4 multiple)
//   acc : [20][N]  atomic accumulator: rows 0..9 spatial_out, 10..19 bilateral_out
#define WS_FJ   0
#define WS_PP   (N * 8)
#define WS_ACC  (N * 8 + N * 12)

__global__ __launch_bounds__(BLOCK) void setup_kernel(const float* __restrict__ feat,
                                                      float* __restrict__ fj) {
    int n = blockIdx.x * BLOCK + threadIdx.x;
    float f[D];
#pragma unroll
    for (int d = 0; d < D; ++d) f[d] = feat[d * N + n];
    float r3 = f[0] * f[0] + f[1] * f[1] + f[2] * f[2];
    float r6 = r3 + f[3] * f[3] + f[4] * f[4] + f[5] * f[5];
#pragma unroll
    for (int d = 0; d < D; ++d) fj[n * 8 + d] = f[d];
    fj[n * 8 + 6] = 0.5f * r3 * CSP;
    fj[n * 8 + 7] = 0.5f * r6 * LOG2E;
}

// do_filter=0: q = unaries (acc is poison -> just zero it). is_last=1: write q to out.
__global__ __launch_bounds__(BLOCK) void combine_kernel(
    const float* __restrict__ unaries, const float* __restrict__ SW,
    const float* __restrict__ BW, const float* __restrict__ CM,
    float* __restrict__ acc, float* __restrict__ pp, float* __restrict__ out,
    int do_filter, int is_last) {
    __shared__ float sSW[100], sBW[100], sCM[100];
    int t = threadIdx.x;
    if (t < 100) { sSW[t] = SW[t]; sBW[t] = BW[t]; sCM[t] = CM[t]; }
    __syncthreads();
    int n = blockIdx.x * BLOCK + t;

    float q[C];
    if (do_filter) {
        float sp[C], bl[C];
#pragma unroll
        for (int k = 0; k < C; ++k) {
            sp[k] = acc[k * N + n];        acc[k * N + n] = 0.0f;
            bl[k] = acc[(C + k) * N + n];  acc[(C + k) * N + n] = 0.0f;
        }
        float msg[C];
#pragma unroll
        for (int c = 0; c < C; ++c) {
            float m = 0.0f;
#pragma unroll
            for (int k = 0; k < C; ++k)
                m += sSW[c * C + k] * sp[k] + sBW[c * C + k] * bl[k];
            msg[c] = m;
        }
#pragma unroll
        for (int c = 0; c < C; ++c) {
            float pw = 0.0f;
#pragma unroll
            for (int k = 0; k < C; ++k) pw += sCM[c * C + k] * msg[k];
            q[c] = unaries[c * N + n] - pw;
        }
    } else {
#pragma unroll
        for (int c = 0; c < C; ++c) q[c] = unaries[c * N + n];
#pragma unroll
        for (int k = 0; k < 2 * C; ++k) acc[k * N + n] = 0.0f;
    }

    if (is_last) {
#pragma unroll
        for (int c = 0; c < C; ++c) out[c * N + n] = q[c];
    } else {
        float m = q[0];
#pragma unroll
        for (int c = 1; c < C; ++c) m = fmaxf(m, q[c]);
        float e[C], s = 0.0f;
#pragma unroll
        for (int c = 0; c < C; ++c) {
            e[c] = __builtin_amdgcn_exp2f((q[c] - m) * LOG2E);
            s += e[c];
        }
        float inv = 1.0f / s;
#pragma unroll
        for (int c = 0; c < C; ++c) pp[n * 12 + c] = e[c] * inv;
        pp[n * 12 + 10] = 0.0f;
        pp[n * 12 + 11] = 0.0f;
    }
}

__global__ __launch_bounds__(BLOCK, 4) void filter_kernel(
    const float* __restrict__ fj, const float* __restrict__ pp,
    float* __restrict__ acc) {
    __shared__ float4 sF[JT * 2];   // [j][8 floats]  =  8 KB
    __shared__ float4 sP[JT * 3];   // [j][12 floats] = 12 KB
    int t = threadIdx.x;
    int itile = blockIdx.x;
    int jc = blockIdx.y;
    int jbase = jc * JT;

    // stage j-chunk into LDS (coalesced float4)
    const float4* gF = (const float4*)(fj + (size_t)jbase * 8);
    for (int k = t; k < JT * 2; k += BLOCK) sF[k] = gF[k];
    const float4* gP = (const float4*)(pp + (size_t)jbase * 12);
    for (int k = t; k < JT * 3; k += BLOCK) sP[k] = gP[k];
    __syncthreads();

    int i = itile * BLOCK + t;
    float4 fiA = ((const float4*)fj)[i * 2 + 0];  // f0..f3
    float4 fiB = ((const float4*)fj)[i * 2 + 1];  // f4, f5, hs'_i, hb'_i
    float nhs = -fiB.z;
    float nhb = -fiB.w;

    // two independent accumulator sets (even/odd j) for fma-chain ILP
    float asp0[C], abl0[C], asp1[C], abl1[C];
#pragma unroll
    for (int k = 0; k < C; ++k) {
        asp0[k] = 0.0f; abl0[k] = 0.0f;
        asp1[k] = 0.0f; abl1[k] = 0.0f;
    }

#pragma unroll 2
    for (int j = 0; j < JT; j += 2) {
        // ---- even j ----
        float4 fA0 = sF[j * 2 + 0];
        float4 fB0 = sF[j * 2 + 1];
        // ---- odd j ----
        float4 fA1 = sF[j * 2 + 2];
        float4 fB1 = sF[j * 2 + 3];

        float d3a = fiA.x * fA0.x + fiA.y * fA0.y + fiA.z * fA0.z;
        float d3b = fiA.x * fA1.x + fiA.y * fA1.y + fiA.z * fA1.z;
        float d6a = d3a + fiA.w * fA0.w + fiB.x * fB0.x + fiB.y * fB0.y;
        float d6b = d3b + fiA.w * fA1.w + fiB.x * fB1.x + fiB.y * fB1.y;

        float wsp0 = __builtin_amdgcn_exp2f(fmaf(d3a, CSP, nhs) - fB0.z);
        float wsp1 = __builtin_amdgcn_exp2f(fmaf(d3b, CSP, nhs) - fB1.z);
        float wbl0 = __builtin_amdgcn_exp2f(fmaf(d6a, LOG2E, nhb) - fB0.w);
        float wbl1 = __builtin_amdgcn_exp2f(fmaf(d6b, LOG2E, nhb) - fB1.w);

        float4 p00 = sP[j * 3 + 0];
        float4 p01 = sP[j * 3 + 1];
        float4 p02 = sP[j * 3 + 2];
        float4 p10 = sP[j * 3 + 3];
        float4 p11 = sP[j * 3 + 4];
        float4 p12 = sP[j * 3 + 5];
        float pj0[C] = {p00.x, p00.y, p00.z, p00.w, p01.x, p01.y, p01.z, p01.w, p02.x, p02.y};
        float pj1[C] = {p10.x, p10.y, p10.z, p10.w, p11.x, p11.y, p11.z, p11.w, p12.x, p12.y};
#pragma unroll
        for (int k = 0; k < C; ++k) {
            asp0[k] = fmaf(wsp0, pj0[k], asp0[k]);
            abl0[k] = fmaf(wbl0, pj0[k], abl0[k]);
            asp1[k] = fmaf(wsp1, pj1[k], asp1[k]);
            abl1[k] = fmaf(wbl1, pj1[k], abl1[k]);
        }
    }

#pragma unroll
    for (int k = 0; k < C; ++k) {
        atomicAdd(&acc[k * N + i], asp0[k] + asp1[k]);
        atomicAdd(&acc[(C + k) * N + i], abl0[k] + abl1[k]);
    }
}

extern "C" void kernel_launch(void* const* d_in, const int* in_sizes, int n_in,
                              void* d_out, int out_size, void* d_ws, size_t ws_size,
                              hipStream_t stream) {
    const float* unaries = (const float*)d_in[0];   // [10, 8192]
    const float* feat    = (const float*)d_in[1];   // [6, 8192]
    const float* SW      = (const float*)d_in[2];   // [10,10]
    const float* BW      = (const float*)d_in[3];   // [10,10]
    const float* CM      = (const float*)d_in[4];   // [10,10]
    float* out = (float*)d_out;

    float* ws  = (float*)d_ws;
    float* fj  = ws + WS_FJ;
    float* pp  = ws + WS_PP;
    float* acc = ws + WS_ACC;

    setup_kernel<<<N / BLOCK, BLOCK, 0, stream>>>(feat, fj);
    // initial softmax of unaries -> pp ; zero acc
    combine_kernel<<<N / BLOCK, BLOCK, 0, stream>>>(unaries, SW, BW, CM, acc, pp, out, 0, 0);
    for (int it = 1; it <= NUM_ITERS; ++it) {
        filter_kernel<<<dim3(ITILES, JCHUNKS), BLOCK, 0, stream>>>(fj, pp, acc);
        combine_kernel<<<N / BLOCK, BLOCK, 0, stream>>>(unaries, SW, BW, CM, acc, pp, out,
                                                        1, it == NUM_ITERS ? 1 : 0);
    }
}

// Round 3
// 289.691 us; speedup vs baseline: 1.3674x; 1.3474x over previous
//
#include <hip/hip_runtime.h>
#include <math.h>

#define N 8192
#define C 10
#define NUM_ITERS 5
#define BLOCK 256
#define JCH 16
#define JT (N / JCH)      /* 512 j's staged per block */
#define IBLK 128          /* i's per block: 4 waves x 32 */
#define NIB (N / IBLK)    /* 64 */
#define LOG2E 1.44269504088896340736f
#define C3 (LOG2E / 64.0f)
#define PROW (JT + 8)     /* padded LDS row for p (f16 elems) */

typedef _Float16 half8 __attribute__((ext_vector_type(8)));
typedef _Float16 half4 __attribute__((ext_vector_type(4)));
typedef float f32x4 __attribute__((ext_vector_type(4)));

// ws byte offsets:
//   ajs half8[N] : j-side spatial aug features   [f*C3 x3, 0,0,0, -h3*C3, 1]
//   ajb half8[N] : j-side bilateral aug features [f*LOG2E x6, -h6*LOG2E, 1]
//   pf  f16[16][N] : softmax probs, rows 10..15 zero
//   acc float[20][N] : rows 0-9 spatial_out, 10-19 bilateral_out (atomic)
#define WS_AJS 0
#define WS_AJB (N * 16)
#define WS_PF  (N * 32)
#define WS_ACC (N * 64)

__global__ __launch_bounds__(BLOCK) void prep_kernel(const float* __restrict__ feat,
                                                     half8* __restrict__ ajs,
                                                     half8* __restrict__ ajb) {
    int n = blockIdx.x * BLOCK + threadIdx.x;
    float f[6];
#pragma unroll
    for (int d = 0; d < 6; ++d) f[d] = feat[d * N + n];
    float h3 = 0.5f * (f[0] * f[0] + f[1] * f[1] + f[2] * f[2]);
    float h6 = h3 + 0.5f * (f[3] * f[3] + f[4] * f[4] + f[5] * f[5]);
    half8 a = {};
    a[0] = (_Float16)(f[0] * C3);
    a[1] = (_Float16)(f[1] * C3);
    a[2] = (_Float16)(f[2] * C3);
    a[6] = (_Float16)(-h3 * C3);
    a[7] = (_Float16)1.0f;
    ajs[n] = a;
    half8 b;
#pragma unroll
    for (int d = 0; d < 6; ++d) b[d] = (_Float16)(f[d] * LOG2E);
    b[6] = (_Float16)(-h6 * LOG2E);
    b[7] = (_Float16)1.0f;
    ajb[n] = b;
}

// do_filter=0: q=unaries, zero acc.  is_last=1: write q to out (skip softmax).
__global__ __launch_bounds__(BLOCK) void combine_kernel(
    const float* __restrict__ unaries, const float* __restrict__ SW,
    const float* __restrict__ BW, const float* __restrict__ CM,
    float* __restrict__ acc, _Float16* __restrict__ pf, float* __restrict__ out,
    int do_filter, int is_last) {
    __shared__ float sSW[100], sBW[100], sCM[100];
    int t = threadIdx.x;
    if (t < 100) { sSW[t] = SW[t]; sBW[t] = BW[t]; sCM[t] = CM[t]; }
    __syncthreads();
    int n = blockIdx.x * BLOCK + t;

    float q[C];
    if (do_filter) {
        float sp[C], bl[C];
#pragma unroll
        for (int k = 0; k < C; ++k) {
            sp[k] = acc[k * N + n];        acc[k * N + n] = 0.0f;
            bl[k] = acc[(C + k) * N + n];  acc[(C + k) * N + n] = 0.0f;
        }
        float msg[C];
#pragma unroll
        for (int c = 0; c < C; ++c) {
            float m = 0.0f;
#pragma unroll
            for (int k = 0; k < C; ++k)
                m += sSW[c * C + k] * sp[k] + sBW[c * C + k] * bl[k];
            msg[c] = m;
        }
#pragma unroll
        for (int c = 0; c < C; ++c) {
            float pw = 0.0f;
#pragma unroll
            for (int k = 0; k < C; ++k) pw += sCM[c * C + k] * msg[k];
            q[c] = unaries[c * N + n] - pw;
        }
    } else {
#pragma unroll
        for (int c = 0; c < C; ++c) q[c] = unaries[c * N + n];
#pragma unroll
        for (int k = 0; k < 2 * C; ++k) acc[k * N + n] = 0.0f;
    }

    if (is_last) {
#pragma unroll
        for (int c = 0; c < C; ++c) out[c * N + n] = q[c];
    } else {
        float m = q[0];
#pragma unroll
        for (int c = 1; c < C; ++c) m = fmaxf(m, q[c]);
        float e[C], s = 0.0f;
#pragma unroll
        for (int c = 0; c < C; ++c) {
            e[c] = __builtin_amdgcn_exp2f((q[c] - m) * LOG2E);
            s += e[c];
        }
        float inv = 1.0f / s;
#pragma unroll
        for (int c = 0; c < C; ++c) pf[c * N + n] = (_Float16)(e[c] * inv);
#pragma unroll
        for (int c = C; c < 16; ++c) pf[c * N + n] = (_Float16)0.0f;
    }
}

__global__ __launch_bounds__(BLOCK, 4) void filter_kernel(
    const float* __restrict__ feat, const half8* __restrict__ ajs,
    const half8* __restrict__ ajb, const _Float16* __restrict__ pf,
    float* __restrict__ acc) {
    __shared__ half8 ajs_l[JT];            //  8 KB
    __shared__ half8 ajb_l[JT];            //  8 KB
    __shared__ _Float16 p_l[16 * PROW];    // 16.25 KB

    int t = threadIdx.x;
    int ibb = blockIdx.x * IBLK;
    int jbase = blockIdx.y * JT;

    // ---- stage j-chunk: aug features + p rows (coalesced float4) ----
    {
        const float4* s0 = (const float4*)(ajs + jbase);
        const float4* s1 = (const float4*)(ajb + jbase);
        float4* d0 = (float4*)ajs_l;
        float4* d1 = (float4*)ajb_l;
        for (int k = t; k < JT; k += BLOCK) { d0[k] = s0[k]; d1[k] = s1[k]; }
        const float4* ps = (const float4*)pf;
        float4* pd = (float4*)p_l;
        for (int k = t; k < 16 * (JT / 8); k += BLOCK) {
            int c = k >> 6, off = k & 63;
            pd[c * (PROW / 8) + off] = ps[c * (N / 8) + (jbase >> 3) + off];
        }
    }
    __syncthreads();

    int lane = t & 63;
    int w = t >> 6;
    int il = lane & 15;
    int quad = lane >> 4;
    int i0 = ibb + w * 32;   // this wave's 32 i's: subtile0 = i0.., subtile1 = i0+16..

    // B1 fragments (i-side aug features), quad-0 lanes hold k=0..7, rest zero
    half8 b1s0 = {}, b1s1 = {}, b1b0 = {}, b1b1 = {};
    if (lane < 16) {
#pragma unroll
        for (int s = 0; s < 2; ++s) {
            int i = i0 + s * 16 + lane;
            float g0 = feat[0 * N + i], g1 = feat[1 * N + i], g2 = feat[2 * N + i];
            float g3 = feat[3 * N + i], g4 = feat[4 * N + i], g5 = feat[5 * N + i];
            float h3 = 0.5f * (g0 * g0 + g1 * g1 + g2 * g2);
            float h6 = h3 + 0.5f * (g3 * g3 + g4 * g4 + g5 * g5);
            half8 vs = {};
            vs[0] = (_Float16)g0; vs[1] = (_Float16)g1; vs[2] = (_Float16)g2;
            vs[6] = (_Float16)1.0f; vs[7] = (_Float16)(-h3 * C3);
            half8 vb;
            vb[0] = (_Float16)g0; vb[1] = (_Float16)g1; vb[2] = (_Float16)g2;
            vb[3] = (_Float16)g3; vb[4] = (_Float16)g4; vb[5] = (_Float16)g5;
            vb[6] = (_Float16)1.0f; vb[7] = (_Float16)(-h6 * LOG2E);
            if (s == 0) { b1s0 = vs; b1b0 = vb; } else { b1s1 = vs; b1b1 = vb; }
        }
    }

    f32x4 as0 = {0.f, 0.f, 0.f, 0.f}, as1 = {0.f, 0.f, 0.f, 0.f};
    f32x4 ab0 = {0.f, 0.f, 0.f, 0.f}, ab1 = {0.f, 0.f, 0.f, 0.f};
    const f32x4 zero = {0.f, 0.f, 0.f, 0.f};

    for (int jb = 0; jb < JT; jb += 16) {
        // A1 fragments: j-side aug features (quad-0 lanes), 16 j's
        half8 a1s = {}, a1b = {};
        if (lane < 16) { a1s = ajs_l[jb + lane]; a1b = ajb_l[jb + lane]; }
        // B2 fragment: p[c=il][jbase+jb+quad*4 .. +3]
        half4 b2 = *(const half4*)&p_l[il * PROW + jb + quad * 4];

        // GEMM-1 -> S^T[j][i] (C/D layout) -> exp2 -> in-lane == A2 fragment
        f32x4 d;
        half4 a2;

        d = __builtin_amdgcn_mfma_f32_16x16x32_f16(a1s, b1s0, zero, 0, 0, 0);
        a2[0] = (_Float16)__builtin_amdgcn_exp2f(d[0]);
        a2[1] = (_Float16)__builtin_amdgcn_exp2f(d[1]);
        a2[2] = (_Float16)__builtin_amdgcn_exp2f(d[2]);
        a2[3] = (_Float16)__builtin_amdgcn_exp2f(d[3]);
        as0 = __builtin_amdgcn_mfma_f32_16x16x16f16(a2, b2, as0, 0, 0, 0);

        d = __builtin_amdgcn_mfma_f32_16x16x32_f16(a1s, b1s1, zero, 0, 0, 0);
        a2[0] = (_Float16)__builtin_amdgcn_exp2f(d[0]);
        a2[1] = (_Float16)__builtin_amdgcn_exp2f(d[1]);
        a2[2] = (_Float16)__builtin_amdgcn_exp2f(d[2]);
        a2[3] = (_Float16)__builtin_amdgcn_exp2f(d[3]);
        as1 = __builtin_amdgcn_mfma_f32_16x16x16f16(a2, b2, as1, 0, 0, 0);

        d = __builtin_amdgcn_mfma_f32_16x16x32_f16(a1b, b1b0, zero, 0, 0, 0);
        a2[0] = (_Float16)__builtin_amdgcn_exp2f(d[0]);
        a2[1] = (_Float16)__builtin_amdgcn_exp2f(d[1]);
        a2[2] = (_Float16)__builtin_amdgcn_exp2f(d[2]);
        a2[3] = (_Float16)__builtin_amdgcn_exp2f(d[3]);
        ab0 = __builtin_amdgcn_mfma_f32_16x16x16f16(a2, b2, ab0, 0, 0, 0);

        d = __builtin_amdgcn_mfma_f32_16x16x32_f16(a1b, b1b1, zero, 0, 0, 0);
        a2[0] = (_Float16)__builtin_amdgcn_exp2f(d[0]);
        a2[1] = (_Float16)__builtin_amdgcn_exp2f(d[1]);
        a2[2] = (_Float16)__builtin_amdgcn_exp2f(d[2]);
        a2[3] = (_Float16)__builtin_amdgcn_exp2f(d[3]);
        ab1 = __builtin_amdgcn_mfma_f32_16x16x16f16(a2, b2, ab1, 0, 0, 0);
    }

    // writeout: lane holds D2[i_off = quad*4+r][c = il] per subtile/filter
    if (il < C) {
#pragma unroll
        for (int r = 0; r < 4; ++r) {
            int ia = i0 + quad * 4 + r;
            int ib2 = ia + 16;
            atomicAdd(&acc[il * N + ia], as0[r]);
            atomicAdd(&acc[il * N + ib2], as1[r]);
            atomicAdd(&acc[(C + il) * N + ia], ab0[r]);
            atomicAdd(&acc[(C + il) * N + ib2], ab1[r]);
        }
    }
}

extern "C" void kernel_launch(void* const* d_in, const int* in_sizes, int n_in,
                              void* d_out, int out_size, void* d_ws, size_t ws_size,
                              hipStream_t stream) {
    const float* unaries = (const float*)d_in[0];   // [10, 8192]
    const float* feat    = (const float*)d_in[1];   // [6, 8192]
    const float* SW      = (const float*)d_in[2];   // [10,10]
    const float* BW      = (const float*)d_in[3];   // [10,10]
    const float* CM      = (const float*)d_in[4];   // [10,10]
    float* out = (float*)d_out;

    char* ws = (char*)d_ws;
    half8* ajs    = (half8*)(ws + WS_AJS);
    half8* ajb    = (half8*)(ws + WS_AJB);
    _Float16* pf  = (_Float16*)(ws + WS_PF);
    float* acc    = (float*)(ws + WS_ACC);

    prep_kernel<<<N / BLOCK, BLOCK, 0, stream>>>(feat, ajs, ajb);
    combine_kernel<<<N / BLOCK, BLOCK, 0, stream>>>(unaries, SW, BW, CM, acc, pf, out, 0, 0);
    for (int it = 1; it <= NUM_ITERS; ++it) {
        filter_kernel<<<dim3(NIB, JCH), BLOCK, 0, stream>>>(feat, ajs, ajb, pf, acc);
        combine_kernel<<<N / BLOCK, BLOCK, 0, stream>>>(unaries, SW, BW, CM, acc, pf, out,
                                                        1, it == NUM_ITERS ? 1 : 0);
    }
}

// Round 4
// 277.697 us; speedup vs baseline: 1.4264x; 1.0432x over previous
//
#include <hip/hip_runtime.h>
#include <math.h>

#define N 8192
#define C 10
#define NUM_ITERS 5
#define BLOCK 256
#define JCH 16
#define JT (N / JCH)      /* 512 j's staged per block */
#define IBLK 128          /* i's per block: 4 waves x 32 */
#define NIB (N / IBLK)    /* 64 */
#define LOG2E 1.44269504088896340736f
#define C3 (LOG2E / 64.0f)
#define PROW (JT + 8)     /* padded LDS row for p (f16 elems) */

typedef _Float16 half8 __attribute__((ext_vector_type(8)));
typedef _Float16 half4 __attribute__((ext_vector_type(4)));
typedef float f32x4 __attribute__((ext_vector_type(4)));

// ws byte offsets:
//   ajs half8[N] : j-side spatial aug features   [f*C3 x3, 0, 0,0,-h3*C3, 1] (two half4s)
//   ajb half8[N] : j-side bilateral aug features [f*L2E x4, f4*L2E,f5*L2E,-h6*L2E, 1]
//   pf  f16[16][N] : softmax probs, rows 10..15 zero
//   acc float[20][N] : rows 0-9 spatial_out, 10-19 bilateral_out (atomic)
#define WS_AJS 0
#define WS_AJB (N * 16)
#define WS_PF  (N * 32)
#define WS_ACC (N * 64)

// do_filter=0: q=unaries, zero acc, ALSO build ajs/ajb (prep fused).
// is_last=1: write q to out (skip softmax).
__global__ __launch_bounds__(BLOCK) void combine_kernel(
    const float* __restrict__ unaries, const float* __restrict__ feat,
    const float* __restrict__ SW, const float* __restrict__ BW,
    const float* __restrict__ CM, float* __restrict__ acc,
    _Float16* __restrict__ pf, half8* __restrict__ ajs, half8* __restrict__ ajb,
    float* __restrict__ out, int do_filter, int is_last) {
    __shared__ float sSW[100], sBW[100], sCM[100];
    int t = threadIdx.x;
    if (t < 100) { sSW[t] = SW[t]; sBW[t] = BW[t]; sCM[t] = CM[t]; }
    __syncthreads();
    int n = blockIdx.x * BLOCK + t;

    float q[C];
    if (do_filter) {
        float sp[C], bl[C];
#pragma unroll
        for (int k = 0; k < C; ++k) {
            sp[k] = acc[k * N + n];        acc[k * N + n] = 0.0f;
            bl[k] = acc[(C + k) * N + n];  acc[(C + k) * N + n] = 0.0f;
        }
        float msg[C];
#pragma unroll
        for (int c = 0; c < C; ++c) {
            float m = 0.0f;
#pragma unroll
            for (int k = 0; k < C; ++k)
                m += sSW[c * C + k] * sp[k] + sBW[c * C + k] * bl[k];
            msg[c] = m;
        }
#pragma unroll
        for (int c = 0; c < C; ++c) {
            float pw = 0.0f;
#pragma unroll
            for (int k = 0; k < C; ++k) pw += sCM[c * C + k] * msg[k];
            q[c] = unaries[c * N + n] - pw;
        }
    } else {
#pragma unroll
        for (int c = 0; c < C; ++c) q[c] = unaries[c * N + n];
#pragma unroll
        for (int k = 0; k < 2 * C; ++k) acc[k * N + n] = 0.0f;
        // prep: augmented j-side feature vectors
        float f[6];
#pragma unroll
        for (int d = 0; d < 6; ++d) f[d] = feat[d * N + n];
        float h3 = 0.5f * (f[0] * f[0] + f[1] * f[1] + f[2] * f[2]);
        float h6 = h3 + 0.5f * (f[3] * f[3] + f[4] * f[4] + f[5] * f[5]);
        half8 a = {};
        a[0] = (_Float16)(f[0] * C3);
        a[1] = (_Float16)(f[1] * C3);
        a[2] = (_Float16)(f[2] * C3);
        a[6] = (_Float16)(-h3 * C3);
        a[7] = (_Float16)1.0f;
        ajs[n] = a;
        half8 b;
#pragma unroll
        for (int d = 0; d < 6; ++d) b[d] = (_Float16)(f[d] * LOG2E);
        b[6] = (_Float16)(-h6 * LOG2E);
        b[7] = (_Float16)1.0f;
        ajb[n] = b;
    }

    if (is_last) {
#pragma unroll
        for (int c = 0; c < C; ++c) out[c * N + n] = q[c];
    } else {
        float m = q[0];
#pragma unroll
        for (int c = 1; c < C; ++c) m = fmaxf(m, q[c]);
        float e[C], s = 0.0f;
#pragma unroll
        for (int c = 0; c < C; ++c) {
            e[c] = __builtin_amdgcn_exp2f((q[c] - m) * LOG2E);
            s += e[c];
        }
        float inv = 1.0f / s;
#pragma unroll
        for (int c = 0; c < C; ++c) pf[c * N + n] = (_Float16)(e[c] * inv);
#pragma unroll
        for (int c = C; c < 16; ++c) pf[c * N + n] = (_Float16)0.0f;
    }
}

static __device__ inline half4 expcvt(f32x4 d) {
    half4 r;
    r[0] = (_Float16)__builtin_amdgcn_exp2f(d[0]);
    r[1] = (_Float16)__builtin_amdgcn_exp2f(d[1]);
    r[2] = (_Float16)__builtin_amdgcn_exp2f(d[2]);
    r[3] = (_Float16)__builtin_amdgcn_exp2f(d[3]);
    return r;
}

__global__ __launch_bounds__(BLOCK, 4) void filter_kernel(
    const float* __restrict__ feat, const half4* __restrict__ ajs,
    const half4* __restrict__ ajb, const _Float16* __restrict__ pf,
    float* __restrict__ acc) {
    __shared__ half4 ajs_l[JT * 2];        //  8 KB  [j][h]
    __shared__ half4 ajb_l[JT * 2];        //  8 KB
    __shared__ _Float16 p_l[16 * PROW];    // 16.25 KB

    int t = threadIdx.x;
    int ibb = blockIdx.x * IBLK;
    int jbase = blockIdx.y * JT;

    // ---- stage j-chunk (coalesced float4) ----
    {
        const float4* s0 = (const float4*)(ajs + (size_t)jbase * 2);
        const float4* s1 = (const float4*)(ajb + (size_t)jbase * 2);
        float4* d0 = (float4*)ajs_l;
        float4* d1 = (float4*)ajb_l;
        for (int k = t; k < JT; k += BLOCK) { d0[k] = s0[k]; d1[k] = s1[k]; }
        const float4* ps = (const float4*)pf;
        float4* pd = (float4*)p_l;
        for (int k = t; k < 16 * (JT / 8); k += BLOCK) {
            int c = k >> 6, off = k & 63;
            pd[c * (PROW / 8) + off] = ps[c * (N / 8) + (jbase >> 3) + off];
        }
    }
    __syncthreads();

    int lane = t & 63;
    int w = t >> 6;
    int il = lane & 15;
    int quad = lane >> 4;
    int h = quad & 1;
    bool klo = (quad < 2);
    int i0 = ibb + w * 32;   // wave's 32 i's: subtile0 = i0.., subtile1 = i0+16..

    const half4 hz = {};

    // B1 fragments (i-side aug), K=16 layout: lane holds B[k=quad*4+r][n=il]
    half4 b1s0, b1s1, b1b0, b1b1;
#pragma unroll
    for (int s = 0; s < 2; ++s) {
        int i = i0 + s * 16 + il;
        float g0 = feat[0 * N + i], g1 = feat[1 * N + i], g2 = feat[2 * N + i];
        float g3 = feat[3 * N + i], g4 = feat[4 * N + i], g5 = feat[5 * N + i];
        float h3 = 0.5f * (g0 * g0 + g1 * g1 + g2 * g2);
        float h6 = h3 + 0.5f * (g3 * g3 + g4 * g4 + g5 * g5);
        half4 slo = {(_Float16)g0, (_Float16)g1, (_Float16)g2, (_Float16)0.0f};
        half4 shi = {(_Float16)0.0f, (_Float16)0.0f, (_Float16)1.0f, (_Float16)(-h3 * C3)};
        half4 blo = {(_Float16)g0, (_Float16)g1, (_Float16)g2, (_Float16)g3};
        half4 bhi = {(_Float16)g4, (_Float16)g5, (_Float16)1.0f, (_Float16)(-h6 * LOG2E)};
        half4 vs = klo ? (h ? shi : slo) : hz;
        half4 vb = klo ? (h ? bhi : blo) : hz;
        if (s == 0) { b1s0 = vs; b1b0 = vb; } else { b1s1 = vs; b1b1 = vb; }
    }

    f32x4 as0 = {0.f, 0.f, 0.f, 0.f}, as1 = {0.f, 0.f, 0.f, 0.f};
    f32x4 ab0 = {0.f, 0.f, 0.f, 0.f}, ab1 = {0.f, 0.f, 0.f, 0.f};
    const f32x4 zero = {0.f, 0.f, 0.f, 0.f};

#pragma unroll 2
    for (int jb = 0; jb < JT; jb += 32) {
        int j0 = jb, j1 = jb + 16;
        // hoisted LDS reads (both groups) so latency overlaps
        half4 vs0 = ajs_l[(j0 + il) * 2 + h];
        half4 vb0 = ajb_l[(j0 + il) * 2 + h];
        half4 vs1 = ajs_l[(j1 + il) * 2 + h];
        half4 vb1 = ajb_l[(j1 + il) * 2 + h];
        half4 p2_0 = *(const half4*)&p_l[il * PROW + j0 + quad * 4];
        half4 p2_1 = *(const half4*)&p_l[il * PROW + j1 + quad * 4];
        half4 a1s_0 = klo ? vs0 : hz;
        half4 a1b_0 = klo ? vb0 : hz;
        half4 a1s_1 = klo ? vs1 : hz;
        half4 a1b_1 = klo ? vb1 : hz;

        // GEMM-1: S^T[j][i] in C/D layout (8 independent chains)
        f32x4 d0 = __builtin_amdgcn_mfma_f32_16x16x16f16(a1s_0, b1s0, zero, 0, 0, 0);
        f32x4 d1 = __builtin_amdgcn_mfma_f32_16x16x16f16(a1s_0, b1s1, zero, 0, 0, 0);
        f32x4 d2 = __builtin_amdgcn_mfma_f32_16x16x16f16(a1b_0, b1b0, zero, 0, 0, 0);
        f32x4 d3 = __builtin_amdgcn_mfma_f32_16x16x16f16(a1b_0, b1b1, zero, 0, 0, 0);
        f32x4 d4 = __builtin_amdgcn_mfma_f32_16x16x16f16(a1s_1, b1s0, zero, 0, 0, 0);
        f32x4 d5 = __builtin_amdgcn_mfma_f32_16x16x16f16(a1s_1, b1s1, zero, 0, 0, 0);
        f32x4 d6 = __builtin_amdgcn_mfma_f32_16x16x16f16(a1b_1, b1b0, zero, 0, 0, 0);
        f32x4 d7 = __builtin_amdgcn_mfma_f32_16x16x16f16(a1b_1, b1b1, zero, 0, 0, 0);

        // exp2 + cvt: C/D layout == A-operand layout of 16x16x16f16 (k=quad*4+r)
        half4 w0 = expcvt(d0), w1 = expcvt(d1), w2 = expcvt(d2), w3 = expcvt(d3);
        half4 w4 = expcvt(d4), w5 = expcvt(d5), w6 = expcvt(d6), w7 = expcvt(d7);

        // GEMM-2: out[i][c] += w[i][j] * p[c][j]
        as0 = __builtin_amdgcn_mfma_f32_16x16x16f16(w0, p2_0, as0, 0, 0, 0);
        as1 = __builtin_amdgcn_mfma_f32_16x16x16f16(w1, p2_0, as1, 0, 0, 0);
        ab0 = __builtin_amdgcn_mfma_f32_16x16x16f16(w2, p2_0, ab0, 0, 0, 0);
        ab1 = __builtin_amdgcn_mfma_f32_16x16x16f16(w3, p2_0, ab1, 0, 0, 0);
        as0 = __builtin_amdgcn_mfma_f32_16x16x16f16(w4, p2_1, as0, 0, 0, 0);
        as1 = __builtin_amdgcn_mfma_f32_16x16x16f16(w5, p2_1, as1, 0, 0, 0);
        ab0 = __builtin_amdgcn_mfma_f32_16x16x16f16(w6, p2_1, ab0, 0, 0, 0);
        ab1 = __builtin_amdgcn_mfma_f32_16x16x16f16(w7, p2_1, ab1, 0, 0, 0);
    }

    // writeout: lane holds D2[i_off = quad*4+r][c = il] per subtile/filter
    if (il < C) {
#pragma unroll
        for (int r = 0; r < 4; ++r) {
            int ia = i0 + quad * 4 + r;
            int ib2 = ia + 16;
            atomicAdd(&acc[il * N + ia], as0[r]);
            atomicAdd(&acc[il * N + ib2], as1[r]);
            atomicAdd(&acc[(C + il) * N + ia], ab0[r]);
            atomicAdd(&acc[(C + il) * N + ib2], ab1[r]);
        }
    }
}

extern "C" void kernel_launch(void* const* d_in, const int* in_sizes, int n_in,
                              void* d_out, int out_size, void* d_ws, size_t ws_size,
                              hipStream_t stream) {
    const float* unaries = (const float*)d_in[0];   // [10, 8192]
    const float* feat    = (const float*)d_in[1];   // [6, 8192]
    const float* SW      = (const float*)d_in[2];   // [10,10]
    const float* BW      = (const float*)d_in[3];   // [10,10]
    const float* CM      = (const float*)d_in[4];   // [10,10]
    float* out = (float*)d_out;

    char* ws = (char*)d_ws;
    half8* ajs    = (half8*)(ws + WS_AJS);
    half8* ajb    = (half8*)(ws + WS_AJB);
    _Float16* pf  = (_Float16*)(ws + WS_PF);
    float* acc    = (float*)(ws + WS_ACC);

    combine_kernel<<<N / BLOCK, BLOCK, 0, stream>>>(unaries, feat, SW, BW, CM, acc,
                                                    pf, ajs, ajb, out, 0, 0);
    for (int it = 1; it <= NUM_ITERS; ++it) {
        filter_kernel<<<dim3(NIB, JCH), BLOCK, 0, stream>>>(feat, (const half4*)ajs,
                                                            (const half4*)ajb, pf, acc);
        combine_kernel<<<N / BLOCK, BLOCK, 0, stream>>>(unaries, feat, SW, BW, CM, acc,
                                                        pf, ajs, ajb, out,
                                                        1, it == NUM_ITERS ? 1 : 0);
    }
}